// Round 18
// baseline (190.887 us; speedup 1.0000x reference)
//
#include <hip/hip_runtime.h>
#include <math.h>

#define RES   48
#define WS    4
#define SSH   2
#define DIM   96
#define HEADS 3
#define HD    32
#define NTOK  64
#define NWAX  12
#define NWIN  (NWAX*NWAX*NWAX)   // 1728

#define TSTR 104   // bf16 stride, quad stride 13 (odd) -> conflict-free b128
#define VSTR 72    // quad stride 9 (odd)
#define PSTR 72
#define HSTR 200   // quad stride 25 (odd)

typedef float f32x4 __attribute__((ext_vector_type(4)));
typedef short s16x8 __attribute__((ext_vector_type(8)));
typedef unsigned u32x4 __attribute__((ext_vector_type(4)));

__device__ __forceinline__ short f2bf(float f) {
    unsigned u = __builtin_bit_cast(unsigned, f);
    u = (u + 0x7FFFu + ((u >> 16) & 1u)) >> 16;
    return (short)u;
}
__device__ __forceinline__ float bf2f(short s) {
    unsigned u = ((unsigned)(unsigned short)s) << 16;
    return __builtin_bit_cast(float, u);
}
// HW packed f32->bf16 (RNE); lo = arg0 (bits 0-15)
__device__ __forceinline__ unsigned cvt_pk(float lo, float hi) {
    unsigned r;
    asm("v_cvt_pk_bf16_f32 %0, %1, %2" : "=v"(r) : "v"(lo), "v"(hi));
    return r;
}
__device__ __forceinline__ float gelu_f(float a) {
    float z = a*(1.5957691216057308f + 0.07135481627159927f*a*a);
    return a / (1.0f + __expf(-z));
}
__device__ __forceinline__ int region(int g) {
    return (g < RES - WS) ? 0 : ((g < RES - SSH) ? 1 : 2);
}
__device__ __forceinline__ int tok_xbase(int b, int wh, int ww, int wd, int t) {
    int gh = wh*WS + (t >> 4);
    int gw = ww*WS + ((t >> 2) & 3);
    int gd = wd*WS + (t & 3);
    int sh = gh + SSH; if (sh >= RES) sh -= RES;
    int sw = gw + SSH; if (sw >= RES) sw -= RES;
    int sd = gd + SSH; if (sd >= RES) sd -= RES;
    return (((b*RES + sh)*RES + sw)*RES + sd)*DIM;
}
__device__ __forceinline__ int tok_cnt(int wh, int ww, int wd, int t) {
    return region(wh*WS + (t >> 4))*9 + region(ww*WS + ((t >> 2) & 3))*3
         + region(wd*WS + (t & 3));
}

// ---------------- merged prep: cpb table + pack weights ----------------
__global__ void prep_kernel(const float* __restrict__ cw1, const float* __restrict__ cb1,
                            const float* __restrict__ cw2,
                            const float* __restrict__ fc1_w, const float* __restrict__ fc2_w,
                            const float* __restrict__ qkv_w, const float* __restrict__ proj_w,
                            float* __restrict__ tbl,
                            short* __restrict__ w1p, short* __restrict__ w2p,
                            short* __restrict__ qkvp, short* __restrict__ projp) {
    int bid = blockIdx.x;
    if (bid < 343) {
        __shared__ float hid[512];
        int ti = bid;
        int a = ti / 49, b = (ti / 7) % 7, c = ti % 7;
        float comp[3] = {(float)(a - 3), (float)(b - 3), (float)(c - 3)};
        float f[3];
        #pragma unroll
        for (int k = 0; k < 3; ++k) {
            float u = (comp[k] / 3.0f) * 8.0f;
            float s = (u > 0.f) ? 1.f : ((u < 0.f) ? -1.f : 0.f);
            f[k] = s * log2f(fabsf(u) + 1.0f) * (1.0f / 3.0f);
        }
        for (int j = threadIdx.x; j < 512; j += blockDim.x) {
            float acc = cb1[j] + f[0]*cw1[j*3+0] + f[1]*cw1[j*3+1] + f[2]*cw1[j*3+2];
            hid[j] = fmaxf(acc, 0.f);
        }
        __syncthreads();
        int tid = threadIdx.x;
        if (tid < 192) {
            int h = tid >> 6, lane = tid & 63;
            float p = 0.f;
            for (int j = lane; j < 512; j += 64) p += cw2[h*512 + j] * hid[j];
            #pragma unroll
            for (int off = 32; off; off >>= 1) p += __shfl_down(p, off, 64);
            if (lane == 0) tbl[ti*3 + h] = p;
        }
    } else if (bid < 343 + 144) {
        int i = (bid - 343)*256 + threadIdx.x;
        if (i >= 36864) return;
        {   // fc1 half-split layout: tile = ((H*12 + j)*3 + c>>5)
            int o = i / 96, c = i - o*96;
            int H = o / 192, rem = o - H*192;
            int wv = rem / 48, n3 = (rem - wv*48) >> 4;
            int tile = ((H*12 + wv*3 + n3)*3) + (c >> 5);
            int lane = ((c >> 3) & 3)*16 + (o & 15);
            w1p[tile*512 + lane*8 + (c & 7)] = f2bf(fc1_w[i]);
        }
        {
            int co = i / 384, oo = i - co*384;
            int tile = (co >> 4)*12 + (oo >> 5);
            int lane = ((oo >> 3) & 3)*16 + (co & 15);
            w2p[tile*512 + lane*8 + (oo & 7)] = f2bf(fc2_w[i]);
        }
    } else {
        int i = (bid - 487)*256 + threadIdx.x;
        if (i < 288*96) {
            int o = i / 96, c = i - o*96;
            int tile = (o >> 4)*3 + (c >> 5);
            int lane = ((c >> 3) & 3)*16 + (o & 15);
            qkvp[tile*512 + lane*8 + (c & 7)] = f2bf(qkv_w[i]);
        }
        if (i < 96*96) {
            int co = i / 96, k = i - co*96;
            int tile = (co >> 4)*3 + (k >> 5);
            int lane = ((k >> 3) & 3)*16 + (co & 15);
            projp[tile*512 + lane*8 + (k & 7)] = f2bf(proj_w[i]);
        }
    }
}

// ---------------- rpb[h][i][j] = 16*sigmoid(tbl[rpi(i,j)][h]) ----------------
__global__ void rpb_kernel(const float* __restrict__ tbl, float* __restrict__ rpb) {
    int bi = blockIdx.x;                 // h*64 + i
    int h = bi >> 6, i = bi & 63;
    int j = threadIdx.x;
    int hi = i >> 4, wi = (i >> 2) & 3, di = i & 3;
    int hj = j >> 4, wj = (j >> 2) & 3, dj = j & 3;
    int idx = (hi - hj + 3)*49 + (wi - wj + 3)*7 + (di - dj + 3);
    float v = tbl[idx*3 + h];
    rpb[(h*64 + i)*64 + j] = 16.0f / (1.0f + expf(-v));
}

// ---------------- fused SwinV2 block: no x staging — af direct from global ----------------
__global__ __launch_bounds__(256, 3)
void swin_fused_kernel(const float* __restrict__ x, const short* __restrict__ qkvp,
                       const float* __restrict__ q_bias, const float* __restrict__ v_bias,
                       const float* __restrict__ logit_scale,
                       const short* __restrict__ projp, const float* __restrict__ proj_b,
                       const float* __restrict__ rpb,
                       const float* __restrict__ g1, const float* __restrict__ b1v,
                       const short* __restrict__ w1p, const float* __restrict__ fc1_b,
                       const short* __restrict__ w2p, const float* __restrict__ fc2_b,
                       const float* __restrict__ g2, const float* __restrict__ b2v,
                       float* __restrict__ out) {
    __shared__ __align__(16) char pool[42496];
    short* q_s = (short*)(pool);          // [0,13312): q -> ao_s -> x1b
    short* k_s = (short*)(pool + 13312);  // [13312,26624): k -> p_s -> hb(lo)
    short* vT  = (short*)(pool + 26624);  // [26624,40448): vT -> hb(hi)
    float* qn_t = (float*)(pool + 40448); // 192 f32
    float* kn_t = qn_t + 192;             // 192 f32 -> ends 41984
    int* xbase_s = (int*)(pool + 41984);  // 64 ints
    int* cnt_s   = (int*)(pool + 42240);  // 64 ints -> ends 42496
    short* p_s  = k_s;
    short* ao_s = q_s;
    short* x1b  = q_s;
    short* hb   = (short*)(pool + 13312); // 64*200*2 = 25600 -> ends 38912

    int tid = threadIdx.x;
    int l   = tid & 63;
    int w   = __builtin_amdgcn_readfirstlane(tid >> 6);
    int lc  = l & 15;
    int lg  = l >> 4;

    int wid = blockIdx.x;
    int b   = wid / NWIN;
    int rem = wid - b*NWIN;
    int wh = rem / (NWAX*NWAX);
    int ww = (rem / NWAX) % NWAX;
    int wd = rem % NWAX;

    // ---- per-token index tables (computed once) ----
    if (tid < NTOK) {
        xbase_s[tid] = tok_xbase(b, wh, ww, wd, tid);
        cnt_s[tid]   = tok_cnt(wh, ww, wd, tid);
    }
    __syncthreads();   // S1

    // ---- x B-fragments DIRECT from global (bit-identical to staged path) ----
    s16x8 af[3][4];
    #pragma unroll
    for (int tt = 0; tt < 4; ++tt) {
        const float* src = x + xbase_s[tt*16 + lc];
        #pragma unroll
        for (int ks = 0; ks < 3; ++ks) {
            float4 a = *reinterpret_cast<const float4*>(src + ks*32 + lg*8);
            float4 c = *reinterpret_cast<const float4*>(src + ks*32 + lg*8 + 4);
            u32x4 p;
            p[0] = cvt_pk(a.x, a.y);
            p[1] = cvt_pk(a.z, a.w);
            p[2] = cvt_pk(c.x, c.y);
            p[3] = cvt_pk(c.z, c.w);
            af[ks][tt] = __builtin_bit_cast(s16x8, p);
        }
    }

    // ---- QKV GEMM, SWAPPED: A = weights (m=outdim), B = x (n=token) ----
    for (int nt = w; nt < 18; nt += 4) {
        int od0 = nt*16 + lg*4;
        f32x4 C[4];
        if (nt < 6) {
            float4 qb = *reinterpret_cast<const float4*>(&q_bias[od0]);
            #pragma unroll
            for (int tt = 0; tt < 4; ++tt) C[tt] = f32x4{qb.x, qb.y, qb.z, qb.w};
        } else if (nt >= 12) {
            float4 vb = *reinterpret_cast<const float4*>(&v_bias[od0 - 192]);
            #pragma unroll
            for (int tt = 0; tt < 4; ++tt) C[tt] = f32x4{vb.x, vb.y, vb.z, vb.w};
        } else {
            #pragma unroll
            for (int tt = 0; tt < 4; ++tt) C[tt] = f32x4{0.f, 0.f, 0.f, 0.f};
        }
        #pragma unroll
        for (int ks = 0; ks < 3; ++ks) {
            s16x8 wf = *reinterpret_cast<const s16x8*>(&qkvp[(nt*3+ks)*512 + l*8]);
            #pragma unroll
            for (int tt = 0; tt < 4; ++tt)
                C[tt] = __builtin_amdgcn_mfma_f32_16x16x32_bf16(wf, af[ks][tt], C[tt], 0, 0, 0);
        }
        if (nt < 6) {
            #pragma unroll
            for (int tt = 0; tt < 4; ++tt) {
                uint2 pv;
                pv.x = cvt_pk(C[tt][0], C[tt][1]);
                pv.y = cvt_pk(C[tt][2], C[tt][3]);
                *reinterpret_cast<uint2*>(&q_s[(tt*16+lc)*TSTR + nt*16 + lg*4]) = pv;
            }
        } else if (nt < 12) {
            #pragma unroll
            for (int tt = 0; tt < 4; ++tt) {
                uint2 pv;
                pv.x = cvt_pk(C[tt][0], C[tt][1]);
                pv.y = cvt_pk(C[tt][2], C[tt][3]);
                *reinterpret_cast<uint2*>(&k_s[(tt*16+lc)*TSTR + (nt-6)*16 + lg*4]) = pv;
            }
        } else {
            int vd0 = (nt-12)*16 + lg*4;
            #pragma unroll
            for (int tt = 0; tt < 4; ++tt) {
                unsigned pA = cvt_pk(C[tt][0], C[tt][1]);
                unsigned pB = cvt_pk(C[tt][2], C[tt][3]);
                int tok = tt*16 + lc;
                vT[(vd0+0)*VSTR + tok] = (short)pA;
                vT[(vd0+1)*VSTR + tok] = (short)(pA >> 16);
                vT[(vd0+2)*VSTR + tok] = (short)pB;
                vT[(vd0+3)*VSTR + tok] = (short)(pB >> 16);
            }
        }
    }

    // ---- rpb prefetch + fold shift-mask (cnt from LDS; float4 rpb loads) ----
    int cq = cnt_s[w*16 + lc];            // qtok per lane
    float biasv[3][4][4];
    {
        int4 ck[4];
        #pragma unroll
        for (int nt = 0; nt < 4; ++nt)
            ck[nt] = *reinterpret_cast<const int4*>(&cnt_s[nt*16 + lg*4]);
        #pragma unroll
        for (int h = 0; h < 3; ++h)
            #pragma unroll
            for (int nt = 0; nt < 4; ++nt) {
                float4 bv = *reinterpret_cast<const float4*>(
                    &rpb[(h*64 + w*16 + lc)*64 + nt*16 + lg*4]);
                biasv[h][nt][0] = (cq != ck[nt].x) ? bv.x - 100.0f : bv.x;
                biasv[h][nt][1] = (cq != ck[nt].y) ? bv.y - 100.0f : bv.y;
                biasv[h][nt][2] = (cq != ck[nt].z) ? bv.z - 100.0f : bv.z;
                biasv[h][nt][3] = (cq != ck[nt].w) ? bv.w - 100.0f : bv.w;
            }
    }
    __syncthreads();   // S3 — q/k/vT complete

    // ---- norm tables (waves 0..2) run CONCURRENTLY with QK^T ----
    if (w < 3) {
        int h = w, i = l;
        float kn = 0.f, qn = 0.f;
        #pragma unroll
        for (int c = 0; c < 4; ++c) {
            s16x8 kv = *reinterpret_cast<const s16x8*>(&k_s[i*TSTR + h*32 + c*8]);
            s16x8 qv = *reinterpret_cast<const s16x8*>(&q_s[i*TSTR + h*32 + c*8]);
            #pragma unroll
            for (int e = 0; e < 8; ++e) {
                float fk = bf2f(kv[e]); kn += fk*fk;
                float fq = bf2f(qv[e]); qn += fq*fq;
            }
        }
        float sc = __expf(fminf(logit_scale[h], 4.605170185988092f));
        kn_t[h*64 + i] = 1.0f / fmaxf(sqrtf(kn), 1e-12f);
        qn_t[h*64 + i] = sc / fmaxf(sqrtf(qn), 1e-12f);
    }

    // ---- QK^T, SWAPPED: A = k (m=ktok), B = q (n=qtok) ----
    f32x4 sc_[3][4];
    {
        s16x8 aq[3];
        #pragma unroll
        for (int h = 0; h < 3; ++h)
            aq[h] = *reinterpret_cast<const s16x8*>(&q_s[(w*16+lc)*TSTR + h*32 + lg*8]);
        #pragma unroll
        for (int h = 0; h < 3; ++h)
            #pragma unroll
            for (int nt = 0; nt < 4; ++nt) {
                s16x8 bk = *reinterpret_cast<const s16x8*>(&k_s[(nt*16+lc)*TSTR + h*32 + lg*8]);
                sc_[h][nt] = __builtin_amdgcn_mfma_f32_16x16x32_bf16(bk, aq[h], f32x4{0.f,0.f,0.f,0.f}, 0, 0, 0);
            }
    }
    __syncthreads();   // S4b — q/k reads done, tables written; p_s/ao_s aliases safe

    // ---- per head: scale+bias -> no-max softmax (s <= ~26, e^s fits fp32) -> P -> PV -> ao ----
    #pragma unroll
    for (int h = 0; h < 3; ++h) {
        float qnf = qn_t[h*64 + w*16 + lc];
        float ll = 0.f;
        #pragma unroll
        for (int nt = 0; nt < 4; ++nt) {
            float4 kn4 = *reinterpret_cast<const float4*>(&kn_t[h*64 + nt*16 + lg*4]);
            float e0 = __expf(sc_[h][nt][0]*qnf*kn4.x + biasv[h][nt][0]);
            float e1 = __expf(sc_[h][nt][1]*qnf*kn4.y + biasv[h][nt][1]);
            float e2 = __expf(sc_[h][nt][2]*qnf*kn4.z + biasv[h][nt][2]);
            float e3 = __expf(sc_[h][nt][3]*qnf*kn4.w + biasv[h][nt][3]);
            sc_[h][nt][0] = e0; sc_[h][nt][1] = e1;
            sc_[h][nt][2] = e2; sc_[h][nt][3] = e3;
            ll += e0 + e1 + e2 + e3;
        }
        ll += __shfl_xor(ll, 16, 64);
        ll += __shfl_xor(ll, 32, 64);
        float linv = 1.0f / ll;

        #pragma unroll
        for (int nt = 0; nt < 4; ++nt) {
            uint2 pv;
            pv.x = cvt_pk(sc_[h][nt][0], sc_[h][nt][1]);
            pv.y = cvt_pk(sc_[h][nt][2], sc_[h][nt][3]);
            *reinterpret_cast<uint2*>(&p_s[(w*16+lc)*PSTR + nt*16 + lg*4]) = pv;
        }

        s16x8 ap[2];
        #pragma unroll
        for (int ks = 0; ks < 2; ++ks)
            ap[ks] = *reinterpret_cast<const s16x8*>(&p_s[(w*16+lc)*PSTR + ks*32 + lg*8]);
        #pragma unroll
        for (int dt = 0; dt < 2; ++dt) {
            f32x4 o = {0.f, 0.f, 0.f, 0.f};
            #pragma unroll
            for (int ks = 0; ks < 2; ++ks) {
                s16x8 av = *reinterpret_cast<const s16x8*>(&vT[(h*32 + dt*16 + lc)*VSTR + ks*32 + lg*8]);
                o = __builtin_amdgcn_mfma_f32_16x16x32_bf16(av, ap[ks], o, 0, 0, 0);
            }
            uint2 pv;
            pv.x = cvt_pk(o[0]*linv, o[1]*linv);
            pv.y = cvt_pk(o[2]*linv, o[3]*linv);
            *reinterpret_cast<uint2*>(&ao_s[(w*16+lc)*TSTR + h*32 + dt*16 + lg*4]) = pv;
        }
    }

    // ---- prefetch x residual (consumed in LN1); latency hides under proj ----
    int xbr[4];
    float xres[6][4];
    #pragma unroll
    for (int r = 0; r < 4; ++r) {
        xbr[r] = xbase_s[w*16 + lg*4 + r];
        #pragma unroll
        for (int n2 = 0; n2 < 3; ++n2) {
            xres[n2*2][r]   = x[xbr[r] + n2*32 + lc];
            xres[n2*2+1][r] = x[xbr[r] + n2*32 + 16 + lc];
        }
    }

    // ---- proj (own-wave rows); result in registers ----
    float yv[6][4];
    {
        s16x8 aa[3];
        #pragma unroll
        for (int ks = 0; ks < 3; ++ks)
            aa[ks] = *reinterpret_cast<const s16x8*>(&ao_s[(w*16+lc)*TSTR + ks*32 + lg*8]);
        #pragma unroll
        for (int nt = 0; nt < 6; ++nt) {
            float bias = proj_b[nt*16 + lc];
            f32x4 C = f32x4{bias, bias, bias, bias};
            #pragma unroll
            for (int ks = 0; ks < 3; ++ks) {
                s16x8 bf = *reinterpret_cast<const s16x8*>(&projp[(nt*3+ks)*512 + l*8]);
                C = __builtin_amdgcn_mfma_f32_16x16x32_bf16(aa[ks], bf, C, 0, 0, 0);
            }
            #pragma unroll
            for (int r = 0; r < 4; ++r) yv[nt][r] = C[r];
        }
    }
    // no barrier: LN1/x1b touches only own-wave rows of the q region

    // ---- LN1 + residual (x from prefetched regs); write x1 to bf16 LDS only ----
    #pragma unroll
    for (int r = 0; r < 4; ++r) {
        float s = 0.f, sq = 0.f;
        #pragma unroll
        for (int n = 0; n < 6; ++n) { float v = yv[n][r]; s += v; sq += v*v; }
        #pragma unroll
        for (int m = 1; m < 16; m <<= 1) { s += __shfl_xor(s, m, 64); sq += __shfl_xor(sq, m, 64); }
        float mu  = s * (1.0f/DIM);
        float var = sq * (1.0f/DIM) - mu*mu;
        float rs  = rsqrtf(fmaxf(var, 0.f) + 1e-5f);
        int t = w*16 + lg*4 + r;
        #pragma unroll
        for (int n2 = 0; n2 < 3; ++n2) {
            int c0 = n2*32 + lc;
            float v0 = xres[n2*2][r]   + (yv[n2*2][r]   - mu)*rs*g1[c0]    + b1v[c0];
            float v1 = xres[n2*2+1][r] + (yv[n2*2+1][r] - mu)*rs*g1[c0+16] + b1v[c0+16];
            unsigned pk = cvt_pk(v0, v1);
            x1b[t*TSTR + c0]      = (short)pk;
            x1b[t*TSTR + c0 + 16] = (short)(pk >> 16);
        }
    }
    __syncthreads();   // S6 — all PV vT-reads done; hb region free. LAST barrier.

    // ---- MLP, fully intra-wave (wave owns rows w*16..+15) ----
    s16x8 afx[3];
    #pragma unroll
    for (int ks = 0; ks < 3; ++ks)
        afx[ks] = *reinterpret_cast<const s16x8*>(&x1b[(w*16 + lc)*TSTR + ks*32 + lg*8]);

    f32x4 acc2[6];
    #pragma unroll
    for (int n = 0; n < 6; ++n) {
        float bb = fc2_b[n*16 + lc];
        acc2[n] = f32x4{bb, bb, bb, bb};
    }
    #pragma unroll
    for (int H = 0; H < 2; ++H) {
        f32x4 acc1[12];
        #pragma unroll
        for (int j = 0; j < 12; ++j) {
            float bb = fc1_b[H*192 + j*16 + lc];
            acc1[j] = f32x4{bb, bb, bb, bb};
        }
        #pragma unroll
        for (int ks = 0; ks < 3; ++ks)
            #pragma unroll
            for (int j = 0; j < 12; ++j) {
                s16x8 bf = *reinterpret_cast<const s16x8*>(&w1p[((H*12 + j)*3 + ks)*512 + l*8]);
                acc1[j] = __builtin_amdgcn_mfma_f32_16x16x32_bf16(afx[ks], bf, acc1[j], 0, 0, 0);
            }
        #pragma unroll
        for (int j = 0; j < 12; ++j) {
            int col = j*16 + lc;
            unsigned pA = cvt_pk(gelu_f(acc1[j][0]), gelu_f(acc1[j][1]));
            unsigned pB = cvt_pk(gelu_f(acc1[j][2]), gelu_f(acc1[j][3]));
            int row = w*16 + lg*4;
            hb[(row+0)*HSTR + col] = (short)pA;
            hb[(row+1)*HSTR + col] = (short)(pA >> 16);
            hb[(row+2)*HSTR + col] = (short)pB;
            hb[(row+3)*HSTR + col] = (short)(pB >> 16);
        }
        #pragma unroll
        for (int ksp = 0; ksp < 6; ++ksp) {
            s16x8 afh = *reinterpret_cast<const s16x8*>(&hb[(w*16 + lc)*HSTR + ksp*32 + lg*8]);
            #pragma unroll
            for (int n = 0; n < 6; ++n) {
                s16x8 bf = *reinterpret_cast<const s16x8*>(&w2p[(n*12 + H*6 + ksp)*512 + l*8]);
                acc2[n] = __builtin_amdgcn_mfma_f32_16x16x32_bf16(afh, bf, acc2[n], 0, 0, 0);
            }
        }
    }

    // ---- LN2 + residual (x1 from bf16 LDS) + write ----
    #pragma unroll
    for (int r = 0; r < 4; ++r) {
        float s = 0.f, sq = 0.f;
        #pragma unroll
        for (int n = 0; n < 6; ++n) { float v = acc2[n][r]; s += v; sq += v*v; }
        #pragma unroll
        for (int m = 1; m < 16; m <<= 1) { s += __shfl_xor(s, m, 64); sq += __shfl_xor(sq, m, 64); }
        float mu  = s * (1.0f/DIM);
        float var = sq * (1.0f/DIM) - mu*mu;
        float rs  = rsqrtf(fmaxf(var, 0.f) + 1e-5f);
        int t = w*16 + lg*4 + r;
        int xb = xbr[r];
        #pragma unroll
        for (int n = 0; n < 6; ++n) {
            int c = n*16 + lc;
            float x1f = bf2f(x1b[t*TSTR + c]);
            out[xb + c] = x1f + (acc2[n][r] - mu)*rs*g2[c] + b2v[c];
        }
    }
}

extern "C" void kernel_launch(void* const* d_in, const int* in_sizes, int n_in,
                              void* d_out, int out_size, void* d_ws, size_t ws_size,
                              hipStream_t stream) {
    const float* x      = (const float*)d_in[0];
    const float* qkv_w  = (const float*)d_in[1];
    const float* q_bias = (const float*)d_in[2];
    const float* v_bias = (const float*)d_in[3];
    const float* lscale = (const float*)d_in[4];
    const float* cpb_w1 = (const float*)d_in[5];
    const float* cpb_b1 = (const float*)d_in[6];
    const float* cpb_w2 = (const float*)d_in[7];
    const float* proj_w = (const float*)d_in[8];
    const float* proj_b = (const float*)d_in[9];
    const float* n1g    = (const float*)d_in[10];
    const float* n1b    = (const float*)d_in[11];
    const float* fc1_w  = (const float*)d_in[12];
    const float* fc1_b  = (const float*)d_in[13];
    const float* fc2_w  = (const float*)d_in[14];
    const float* fc2_b  = (const float*)d_in[15];
    const float* n2g    = (const float*)d_in[16];
    const float* n2b    = (const float*)d_in[17];
    float* out = (float*)d_out;

    char* wsb = (char*)d_ws;
    float* tbl  = (float*)wsb;                         // 343*3 f32
    float* rpb  = (float*)(wsb + 8192);                // 3*64*64 f32 (48KB)
    short* w1p  = (short*)(wsb + 65536);               // 36864 bf16
    short* w2p  = (short*)(wsb + 65536 + 73728);       // 36864 bf16
    short* qkvp = (short*)(wsb + 65536 + 147456);      // 27648 bf16
    short* projp= qkvp + 27648;                        // 9216 bf16

    prep_kernel<<<595, 256, 0, stream>>>(cpb_w1, cpb_b1, cpb_w2, fc1_w, fc2_w,
                                         qkv_w, proj_w, tbl, w1p, w2p, qkvp, projp);
    rpb_kernel<<<192, 64, 0, stream>>>(tbl, rpb);
    swin_fused_kernel<<<2*NWIN, 256, 0, stream>>>(x, qkvp, q_bias, v_bias, lscale,
                                                  projp, proj_b, rpb,
                                                  n1g, n1b, w1p, fc1_b, w2p, fc2_b,
                                                  n2g, n2b, out);
}

// Round 19
// 167.516 us; speedup vs baseline: 1.1395x; 1.1395x over previous
//
#include <hip/hip_runtime.h>
#include <math.h>

#define RES   48
#define WS    4
#define SSH   2
#define DIM   96
#define HEADS 3
#define HD    32
#define NTOK  64
#define NWAX  12
#define NWIN  (NWAX*NWAX*NWAX)   // 1728

#define TSTR 104   // bf16 stride, quad stride 13 (odd) -> conflict-free b128
#define VSTR 72    // quad stride 9 (odd)
#define PSTR 72
#define HSTR 200   // quad stride 25 (odd)

typedef float f32x4 __attribute__((ext_vector_type(4)));
typedef short s16x8 __attribute__((ext_vector_type(8)));

__device__ __forceinline__ short f2bf(float f) {
    unsigned u = __builtin_bit_cast(unsigned, f);
    u = (u + 0x7FFFu + ((u >> 16) & 1u)) >> 16;
    return (short)u;
}
__device__ __forceinline__ float bf2f(short s) {
    unsigned u = ((unsigned)(unsigned short)s) << 16;
    return __builtin_bit_cast(float, u);
}
// HW packed f32->bf16 (RNE); lo = arg0 (bits 0-15)
__device__ __forceinline__ unsigned cvt_pk(float lo, float hi) {
    unsigned r;
    asm("v_cvt_pk_bf16_f32 %0, %1, %2" : "=v"(r) : "v"(lo), "v"(hi));
    return r;
}
__device__ __forceinline__ float gelu_f(float a) {
    float z = a*(1.5957691216057308f + 0.07135481627159927f*a*a);
    return a / (1.0f + __expf(-z));
}
__device__ __forceinline__ int region(int g) {
    return (g < RES - WS) ? 0 : ((g < RES - SSH) ? 1 : 2);
}
__device__ __forceinline__ int tok_xbase(int b, int wh, int ww, int wd, int t) {
    int gh = wh*WS + (t >> 4);
    int gw = ww*WS + ((t >> 2) & 3);
    int gd = wd*WS + (t & 3);
    int sh = gh + SSH; if (sh >= RES) sh -= RES;
    int sw = gw + SSH; if (sw >= RES) sw -= RES;
    int sd = gd + SSH; if (sd >= RES) sd -= RES;
    return (((b*RES + sh)*RES + sw)*RES + sd)*DIM;
}
__device__ __forceinline__ int tok_cnt(int wh, int ww, int wd, int t) {
    return region(wh*WS + (t >> 4))*9 + region(ww*WS + ((t >> 2) & 3))*3
         + region(wd*WS + (t & 3));
}

// ---------------- merged prep: cpb table + pack weights ----------------
__global__ void prep_kernel(const float* __restrict__ cw1, const float* __restrict__ cb1,
                            const float* __restrict__ cw2,
                            const float* __restrict__ fc1_w, const float* __restrict__ fc2_w,
                            const float* __restrict__ qkv_w, const float* __restrict__ proj_w,
                            float* __restrict__ tbl,
                            short* __restrict__ w1p, short* __restrict__ w2p,
                            short* __restrict__ qkvp, short* __restrict__ projp) {
    int bid = blockIdx.x;
    if (bid < 343) {
        __shared__ float hid[512];
        int ti = bid;
        int a = ti / 49, b = (ti / 7) % 7, c = ti % 7;
        float comp[3] = {(float)(a - 3), (float)(b - 3), (float)(c - 3)};
        float f[3];
        #pragma unroll
        for (int k = 0; k < 3; ++k) {
            float u = (comp[k] / 3.0f) * 8.0f;
            float s = (u > 0.f) ? 1.f : ((u < 0.f) ? -1.f : 0.f);
            f[k] = s * log2f(fabsf(u) + 1.0f) * (1.0f / 3.0f);
        }
        for (int j = threadIdx.x; j < 512; j += blockDim.x) {
            float acc = cb1[j] + f[0]*cw1[j*3+0] + f[1]*cw1[j*3+1] + f[2]*cw1[j*3+2];
            hid[j] = fmaxf(acc, 0.f);
        }
        __syncthreads();
        int tid = threadIdx.x;
        if (tid < 192) {
            int h = tid >> 6, lane = tid & 63;
            float p = 0.f;
            for (int j = lane; j < 512; j += 64) p += cw2[h*512 + j] * hid[j];
            #pragma unroll
            for (int off = 32; off; off >>= 1) p += __shfl_down(p, off, 64);
            if (lane == 0) tbl[ti*3 + h] = p;
        }
    } else if (bid < 343 + 144) {
        int i = (bid - 343)*256 + threadIdx.x;
        if (i >= 36864) return;
        {   // fc1 half-split layout: tile = ((H*12 + j)*3 + c>>5)
            int o = i / 96, c = i - o*96;
            int H = o / 192, rem = o - H*192;
            int wv = rem / 48, n3 = (rem - wv*48) >> 4;
            int tile = ((H*12 + wv*3 + n3)*3) + (c >> 5);
            int lane = ((c >> 3) & 3)*16 + (o & 15);
            w1p[tile*512 + lane*8 + (c & 7)] = f2bf(fc1_w[i]);
        }
        {
            int co = i / 384, oo = i - co*384;
            int tile = (co >> 4)*12 + (oo >> 5);
            int lane = ((oo >> 3) & 3)*16 + (co & 15);
            w2p[tile*512 + lane*8 + (oo & 7)] = f2bf(fc2_w[i]);
        }
    } else {
        int i = (bid - 487)*256 + threadIdx.x;
        if (i < 288*96) {
            int o = i / 96, c = i - o*96;
            int tile = (o >> 4)*3 + (c >> 5);
            int lane = ((c >> 3) & 3)*16 + (o & 15);
            qkvp[tile*512 + lane*8 + (c & 7)] = f2bf(qkv_w[i]);
        }
        if (i < 96*96) {
            int co = i / 96, k = i - co*96;
            int tile = (co >> 4)*3 + (k >> 5);
            int lane = ((k >> 3) & 3)*16 + (co & 15);
            projp[tile*512 + lane*8 + (k & 7)] = f2bf(proj_w[i]);
        }
    }
}

// ---------------- rpb[h][i][j] = 16*sigmoid(tbl[rpi(i,j)][h]) ----------------
__global__ void rpb_kernel(const float* __restrict__ tbl, float* __restrict__ rpb) {
    int bi = blockIdx.x;                 // h*64 + i
    int h = bi >> 6, i = bi & 63;
    int j = threadIdx.x;
    int hi = i >> 4, wi = (i >> 2) & 3, di = i & 3;
    int hj = j >> 4, wj = (j >> 2) & 3, dj = j & 3;
    int idx = (hi - hj + 3)*49 + (wi - wj + 3)*7 + (di - dj + 3);
    float v = tbl[idx*3 + h];
    rpb[(h*64 + i)*64 + j] = 16.0f / (1.0f + expf(-v));
}

// ---------------- fused SwinV2 block: r14 + residual prefetch before proj ----------------
__global__ __launch_bounds__(256, 3)
void swin_fused_kernel(const float* __restrict__ x, const short* __restrict__ qkvp,
                       const float* __restrict__ q_bias, const float* __restrict__ v_bias,
                       const float* __restrict__ logit_scale,
                       const short* __restrict__ projp, const float* __restrict__ proj_b,
                       const float* __restrict__ rpb,
                       const float* __restrict__ g1, const float* __restrict__ b1v,
                       const short* __restrict__ w1p, const float* __restrict__ fc1_b,
                       const short* __restrict__ w2p, const float* __restrict__ fc2_b,
                       const float* __restrict__ g2, const float* __restrict__ b2v,
                       float* __restrict__ out) {
    __shared__ __align__(16) char pool[42496];
    short* x_s = (short*)(pool);          // [0,13312): x -> q_s -> ao_s -> x1b
    short* k_s = (short*)(pool + 13312);  // [13312,26624): k -> p_s -> hb(lo)
    short* vT  = (short*)(pool + 26624);  // [26624,40448): vT -> hb(hi)
    float* qn_t = (float*)(pool + 40448); // 192 f32
    float* kn_t = qn_t + 192;             // 192 f32 -> ends 41984
    int* xbase_s = (int*)(pool + 41984);  // 64 ints
    int* cnt_s   = (int*)(pool + 42240);  // 64 ints -> ends 42496
    short* q_s  = x_s;
    short* p_s  = k_s;
    short* ao_s = x_s;
    short* x1b  = x_s;
    short* hb   = (short*)(pool + 13312); // 64*200*2 = 25600 -> ends 38912

    int tid = threadIdx.x;
    int l   = tid & 63;
    int w   = __builtin_amdgcn_readfirstlane(tid >> 6);
    int lc  = l & 15;
    int lg  = l >> 4;

    int wid = blockIdx.x;
    int b   = wid / NWIN;
    int rem = wid - b*NWIN;
    int wh = rem / (NWAX*NWAX);
    int ww = (rem / NWAX) % NWAX;
    int wd = rem % NWAX;

    // ---- per-token index tables (computed once) ----
    if (tid < NTOK) {
        xbase_s[tid] = tok_xbase(b, wh, ww, wd, tid);
        cnt_s[tid]   = tok_cnt(wh, ww, wd, tid);
    }
    __syncthreads();   // S1

    // ---- stage x -> bf16 LDS ----
    for (int idx = tid; idx < NTOK*12; idx += 256) {
        int r = idx / 12, g = idx - r*12;
        const float* src = x + xbase_s[r] + g*8;
        float4 a = *reinterpret_cast<const float4*>(src);
        float4 c = *reinterpret_cast<const float4*>(src + 4);
        uint4 v;
        v.x = cvt_pk(a.x, a.y); v.y = cvt_pk(a.z, a.w);
        v.z = cvt_pk(c.x, c.y); v.w = cvt_pk(c.z, c.w);
        *reinterpret_cast<uint4*>(&x_s[r*TSTR + g*8]) = v;
    }
    __syncthreads();   // S2

    // ---- x B-fragments into registers (af[ks][token-tile]), then x region is free ----
    s16x8 af[3][4];
    #pragma unroll
    for (int ks = 0; ks < 3; ++ks)
        #pragma unroll
        for (int tt = 0; tt < 4; ++tt)
            af[ks][tt] = *reinterpret_cast<const s16x8*>(&x_s[(tt*16+lc)*TSTR + ks*32 + lg*8]);
    __syncthreads();   // S2b — all x reads done; q may overwrite

    // ---- QKV GEMM, SWAPPED: A = weights (m=outdim), B = x (n=token) ----
    for (int nt = w; nt < 18; nt += 4) {
        int od0 = nt*16 + lg*4;
        f32x4 C[4];
        if (nt < 6) {
            float4 qb = *reinterpret_cast<const float4*>(&q_bias[od0]);
            #pragma unroll
            for (int tt = 0; tt < 4; ++tt) C[tt] = f32x4{qb.x, qb.y, qb.z, qb.w};
        } else if (nt >= 12) {
            float4 vb = *reinterpret_cast<const float4*>(&v_bias[od0 - 192]);
            #pragma unroll
            for (int tt = 0; tt < 4; ++tt) C[tt] = f32x4{vb.x, vb.y, vb.z, vb.w};
        } else {
            #pragma unroll
            for (int tt = 0; tt < 4; ++tt) C[tt] = f32x4{0.f, 0.f, 0.f, 0.f};
        }
        #pragma unroll
        for (int ks = 0; ks < 3; ++ks) {
            s16x8 wf = *reinterpret_cast<const s16x8*>(&qkvp[(nt*3+ks)*512 + l*8]);
            #pragma unroll
            for (int tt = 0; tt < 4; ++tt)
                C[tt] = __builtin_amdgcn_mfma_f32_16x16x32_bf16(wf, af[ks][tt], C[tt], 0, 0, 0);
        }
        if (nt < 6) {
            #pragma unroll
            for (int tt = 0; tt < 4; ++tt) {
                uint2 pv;
                pv.x = cvt_pk(C[tt][0], C[tt][1]);
                pv.y = cvt_pk(C[tt][2], C[tt][3]);
                *reinterpret_cast<uint2*>(&q_s[(tt*16+lc)*TSTR + nt*16 + lg*4]) = pv;
            }
        } else if (nt < 12) {
            #pragma unroll
            for (int tt = 0; tt < 4; ++tt) {
                uint2 pv;
                pv.x = cvt_pk(C[tt][0], C[tt][1]);
                pv.y = cvt_pk(C[tt][2], C[tt][3]);
                *reinterpret_cast<uint2*>(&k_s[(tt*16+lc)*TSTR + (nt-6)*16 + lg*4]) = pv;
            }
        } else {
            int vd0 = (nt-12)*16 + lg*4;
            #pragma unroll
            for (int tt = 0; tt < 4; ++tt) {
                unsigned pA = cvt_pk(C[tt][0], C[tt][1]);
                unsigned pB = cvt_pk(C[tt][2], C[tt][3]);
                int tok = tt*16 + lc;
                vT[(vd0+0)*VSTR + tok] = (short)pA;
                vT[(vd0+1)*VSTR + tok] = (short)(pA >> 16);
                vT[(vd0+2)*VSTR + tok] = (short)pB;
                vT[(vd0+3)*VSTR + tok] = (short)(pB >> 16);
            }
        }
    }

    // ---- rpb prefetch + fold shift-mask (cnt from LDS; float4 rpb loads) ----
    int cq = cnt_s[w*16 + lc];            // qtok per lane
    float biasv[3][4][4];
    {
        int4 ck[4];
        #pragma unroll
        for (int nt = 0; nt < 4; ++nt)
            ck[nt] = *reinterpret_cast<const int4*>(&cnt_s[nt*16 + lg*4]);
        #pragma unroll
        for (int h = 0; h < 3; ++h)
            #pragma unroll
            for (int nt = 0; nt < 4; ++nt) {
                float4 bv = *reinterpret_cast<const float4*>(
                    &rpb[(h*64 + w*16 + lc)*64 + nt*16 + lg*4]);
                biasv[h][nt][0] = (cq != ck[nt].x) ? bv.x - 100.0f : bv.x;
                biasv[h][nt][1] = (cq != ck[nt].y) ? bv.y - 100.0f : bv.y;
                biasv[h][nt][2] = (cq != ck[nt].z) ? bv.z - 100.0f : bv.z;
                biasv[h][nt][3] = (cq != ck[nt].w) ? bv.w - 100.0f : bv.w;
            }
    }
    __syncthreads();   // S3 — q/k/vT complete

    // ---- norm tables (waves 0..2) run CONCURRENTLY with QK^T ----
    if (w < 3) {
        int h = w, i = l;
        float kn = 0.f, qn = 0.f;
        #pragma unroll
        for (int c = 0; c < 4; ++c) {
            s16x8 kv = *reinterpret_cast<const s16x8*>(&k_s[i*TSTR + h*32 + c*8]);
            s16x8 qv = *reinterpret_cast<const s16x8*>(&q_s[i*TSTR + h*32 + c*8]);
            #pragma unroll
            for (int e = 0; e < 8; ++e) {
                float fk = bf2f(kv[e]); kn += fk*fk;
                float fq = bf2f(qv[e]); qn += fq*fq;
            }
        }
        float sc = __expf(fminf(logit_scale[h], 4.605170185988092f));
        kn_t[h*64 + i] = 1.0f / fmaxf(sqrtf(kn), 1e-12f);
        qn_t[h*64 + i] = sc / fmaxf(sqrtf(qn), 1e-12f);
    }

    // ---- QK^T, SWAPPED: A = k (m=ktok), B = q (n=qtok) ----
    f32x4 sc_[3][4];
    {
        s16x8 aq[3];
        #pragma unroll
        for (int h = 0; h < 3; ++h)
            aq[h] = *reinterpret_cast<const s16x8*>(&q_s[(w*16+lc)*TSTR + h*32 + lg*8]);
        #pragma unroll
        for (int h = 0; h < 3; ++h)
            #pragma unroll
            for (int nt = 0; nt < 4; ++nt) {
                s16x8 bk = *reinterpret_cast<const s16x8*>(&k_s[(nt*16+lc)*TSTR + h*32 + lg*8]);
                sc_[h][nt] = __builtin_amdgcn_mfma_f32_16x16x32_bf16(bk, aq[h], f32x4{0.f,0.f,0.f,0.f}, 0, 0, 0);
            }
    }
    __syncthreads();   // S4b — q/k reads done, tables written; p_s/ao_s aliases safe

    // ---- per head: scale+bias -> no-max softmax (s <= ~26, e^s fits fp32) -> P -> PV -> ao ----
    #pragma unroll
    for (int h = 0; h < 3; ++h) {
        float qnf = qn_t[h*64 + w*16 + lc];
        float ll = 0.f;
        #pragma unroll
        for (int nt = 0; nt < 4; ++nt) {
            float4 kn4 = *reinterpret_cast<const float4*>(&kn_t[h*64 + nt*16 + lg*4]);
            float e0 = __expf(sc_[h][nt][0]*qnf*kn4.x + biasv[h][nt][0]);
            float e1 = __expf(sc_[h][nt][1]*qnf*kn4.y + biasv[h][nt][1]);
            float e2 = __expf(sc_[h][nt][2]*qnf*kn4.z + biasv[h][nt][2]);
            float e3 = __expf(sc_[h][nt][3]*qnf*kn4.w + biasv[h][nt][3]);
            sc_[h][nt][0] = e0; sc_[h][nt][1] = e1;
            sc_[h][nt][2] = e2; sc_[h][nt][3] = e3;
            ll += e0 + e1 + e2 + e3;
        }
        ll += __shfl_xor(ll, 16, 64);
        ll += __shfl_xor(ll, 32, 64);
        float linv = 1.0f / ll;

        #pragma unroll
        for (int nt = 0; nt < 4; ++nt) {
            uint2 pv;
            pv.x = cvt_pk(sc_[h][nt][0], sc_[h][nt][1]);
            pv.y = cvt_pk(sc_[h][nt][2], sc_[h][nt][3]);
            *reinterpret_cast<uint2*>(&p_s[(w*16+lc)*PSTR + nt*16 + lg*4]) = pv;
        }

        s16x8 ap[2];
        #pragma unroll
        for (int ks = 0; ks < 2; ++ks)
            ap[ks] = *reinterpret_cast<const s16x8*>(&p_s[(w*16+lc)*PSTR + ks*32 + lg*8]);
        #pragma unroll
        for (int dt = 0; dt < 2; ++dt) {
            f32x4 o = {0.f, 0.f, 0.f, 0.f};
            #pragma unroll
            for (int ks = 0; ks < 2; ++ks) {
                s16x8 av = *reinterpret_cast<const s16x8*>(&vT[(h*32 + dt*16 + lc)*VSTR + ks*32 + lg*8]);
                o = __builtin_amdgcn_mfma_f32_16x16x32_bf16(av, ap[ks], o, 0, 0, 0);
            }
            uint2 pv;
            pv.x = cvt_pk(o[0]*linv, o[1]*linv);
            pv.y = cvt_pk(o[2]*linv, o[3]*linv);
            *reinterpret_cast<uint2*>(&ao_s[(w*16+lc)*TSTR + h*32 + dt*16 + lg*4]) = pv;
        }
    }

    // ---- prefetch x residual (consumed in LN1); latency hides under proj ----
    int xbr[4];
    float xres[6][4];
    #pragma unroll
    for (int r = 0; r < 4; ++r) {
        xbr[r] = xbase_s[w*16 + lg*4 + r];
        #pragma unroll
        for (int n2 = 0; n2 < 3; ++n2) {
            xres[n2*2][r]   = x[xbr[r] + n2*32 + lc];
            xres[n2*2+1][r] = x[xbr[r] + n2*32 + 16 + lc];
        }
    }

    // ---- proj (own-wave rows); result in registers ----
    float yv[6][4];
    {
        s16x8 aa[3];
        #pragma unroll
        for (int ks = 0; ks < 3; ++ks)
            aa[ks] = *reinterpret_cast<const s16x8*>(&ao_s[(w*16+lc)*TSTR + ks*32 + lg*8]);
        #pragma unroll
        for (int nt = 0; nt < 6; ++nt) {
            float bias = proj_b[nt*16 + lc];
            f32x4 C = f32x4{bias, bias, bias, bias};
            #pragma unroll
            for (int ks = 0; ks < 3; ++ks) {
                s16x8 bf = *reinterpret_cast<const s16x8*>(&projp[(nt*3+ks)*512 + l*8]);
                C = __builtin_amdgcn_mfma_f32_16x16x32_bf16(aa[ks], bf, C, 0, 0, 0);
            }
            #pragma unroll
            for (int r = 0; r < 4; ++r) yv[nt][r] = C[r];
        }
    }
    // no barrier needed: LN1/x1b touches only own-wave rows of the x region

    // ---- LN1 + residual (x from prefetched regs); write x1 to bf16 LDS only ----
    #pragma unroll
    for (int r = 0; r < 4; ++r) {
        float s = 0.f, sq = 0.f;
        #pragma unroll
        for (int n = 0; n < 6; ++n) { float v = yv[n][r]; s += v; sq += v*v; }
        #pragma unroll
        for (int m = 1; m < 16; m <<= 1) { s += __shfl_xor(s, m, 64); sq += __shfl_xor(sq, m, 64); }
        float mu  = s * (1.0f/DIM);
        float var = sq * (1.0f/DIM) - mu*mu;
        float rs  = rsqrtf(fmaxf(var, 0.f) + 1e-5f);
        int t = w*16 + lg*4 + r;
        #pragma unroll
        for (int n2 = 0; n2 < 3; ++n2) {
            int c0 = n2*32 + lc;
            float v0 = xres[n2*2][r]   + (yv[n2*2][r]   - mu)*rs*g1[c0]    + b1v[c0];
            float v1 = xres[n2*2+1][r] + (yv[n2*2+1][r] - mu)*rs*g1[c0+16] + b1v[c0+16];
            unsigned pk = cvt_pk(v0, v1);
            x1b[t*TSTR + c0]      = (short)pk;
            x1b[t*TSTR + c0 + 16] = (short)(pk >> 16);
        }
    }
    __syncthreads();   // S6 — all PV vT-reads done; hb region free. LAST barrier.

    // ---- MLP, fully intra-wave (wave owns rows w*16..+15) ----
    s16x8 afx[3];
    #pragma unroll
    for (int ks = 0; ks < 3; ++ks)
        afx[ks] = *reinterpret_cast<const s16x8*>(&x1b[(w*16 + lc)*TSTR + ks*32 + lg*8]);

    f32x4 acc2[6];
    #pragma unroll
    for (int n = 0; n < 6; ++n) {
        float bb = fc2_b[n*16 + lc];
        acc2[n] = f32x4{bb, bb, bb, bb};
    }
    #pragma unroll
    for (int H = 0; H < 2; ++H) {
        f32x4 acc1[12];
        #pragma unroll
        for (int j = 0; j < 12; ++j) {
            float bb = fc1_b[H*192 + j*16 + lc];
            acc1[j] = f32x4{bb, bb, bb, bb};
        }
        #pragma unroll
        for (int ks = 0; ks < 3; ++ks)
            #pragma unroll
            for (int j = 0; j < 12; ++j) {
                s16x8 bf = *reinterpret_cast<const s16x8*>(&w1p[((H*12 + j)*3 + ks)*512 + l*8]);
                acc1[j] = __builtin_amdgcn_mfma_f32_16x16x32_bf16(afx[ks], bf, acc1[j], 0, 0, 0);
            }
        #pragma unroll
        for (int j = 0; j < 12; ++j) {
            int col = j*16 + lc;
            unsigned pA = cvt_pk(gelu_f(acc1[j][0]), gelu_f(acc1[j][1]));
            unsigned pB = cvt_pk(gelu_f(acc1[j][2]), gelu_f(acc1[j][3]));
            int row = w*16 + lg*4;
            hb[(row+0)*HSTR + col] = (short)pA;
            hb[(row+1)*HSTR + col] = (short)(pA >> 16);
            hb[(row+2)*HSTR + col] = (short)pB;
            hb[(row+3)*HSTR + col] = (short)(pB >> 16);
        }
        #pragma unroll
        for (int ksp = 0; ksp < 6; ++ksp) {
            s16x8 afh = *reinterpret_cast<const s16x8*>(&hb[(w*16 + lc)*HSTR + ksp*32 + lg*8]);
            #pragma unroll
            for (int n = 0; n < 6; ++n) {
                s16x8 bf = *reinterpret_cast<const s16x8*>(&w2p[(n*12 + H*6 + ksp)*512 + l*8]);
                acc2[n] = __builtin_amdgcn_mfma_f32_16x16x32_bf16(afh, bf, acc2[n], 0, 0, 0);
            }
        }
    }

    // ---- LN2 + residual (x1 from bf16 LDS) + write ----
    #pragma unroll
    for (int r = 0; r < 4; ++r) {
        float s = 0.f, sq = 0.f;
        #pragma unroll
        for (int n = 0; n < 6; ++n) { float v = acc2[n][r]; s += v; sq += v*v; }
        #pragma unroll
        for (int m = 1; m < 16; m <<= 1) { s += __shfl_xor(s, m, 64); sq += __shfl_xor(sq, m, 64); }
        float mu  = s * (1.0f/DIM);
        float var = sq * (1.0f/DIM) - mu*mu;
        float rs  = rsqrtf(fmaxf(var, 0.f) + 1e-5f);
        int t = w*16 + lg*4 + r;
        int xb = xbr[r];
        #pragma unroll
        for (int n = 0; n < 6; ++n) {
            int c = n*16 + lc;
            float x1f = bf2f(x1b[t*TSTR + c]);
            out[xb + c] = x1f + (acc2[n][r] - mu)*rs*g2[c] + b2v[c];
        }
    }
}

extern "C" void kernel_launch(void* const* d_in, const int* in_sizes, int n_in,
                              void* d_out, int out_size, void* d_ws, size_t ws_size,
                              hipStream_t stream) {
    const float* x      = (const float*)d_in[0];
    const float* qkv_w  = (const float*)d_in[1];
    const float* q_bias = (const float*)d_in[2];
    const float* v_bias = (const float*)d_in[3];
    const float* lscale = (const float*)d_in[4];
    const float* cpb_w1 = (const float*)d_in[5];
    const float* cpb_b1 = (const float*)d_in[6];
    const float* cpb_w2 = (const float*)d_in[7];
    const float* proj_w = (const float*)d_in[8];
    const float* proj_b = (const float*)d_in[9];
    const float* n1g    = (const float*)d_in[10];
    const float* n1b    = (const float*)d_in[11];
    const float* fc1_w  = (const float*)d_in[12];
    const float* fc1_b  = (const float*)d_in[13];
    const float* fc2_w  = (const float*)d_in[14];
    const float* fc2_b  = (const float*)d_in[15];
    const float* n2g    = (const float*)d_in[16];
    const float* n2b    = (const float*)d_in[17];
    float* out = (float*)d_out;

    char* wsb = (char*)d_ws;
    float* tbl  = (float*)wsb;                         // 343*3 f32
    float* rpb  = (float*)(wsb + 8192);                // 3*64*64 f32 (48KB)
    short* w1p  = (short*)(wsb + 65536);               // 36864 bf16
    short* w2p  = (short*)(wsb + 65536 + 73728);       // 36864 bf16
    short* qkvp = (short*)(wsb + 65536 + 147456);      // 27648 bf16
    short* projp= qkvp + 27648;                        // 9216 bf16

    prep_kernel<<<595, 256, 0, stream>>>(cpb_w1, cpb_b1, cpb_w2, fc1_w, fc2_w,
                                         qkv_w, proj_w, tbl, w1p, w2p, qkvp, projp);
    rpb_kernel<<<192, 64, 0, stream>>>(tbl, rpb);
    swin_fused_kernel<<<2*NWIN, 256, 0, stream>>>(x, qkvp, q_bias, v_bias, lscale,
                                                  projp, proj_b, rpb,
                                                  n1g, n1b, w1p, fc1_b, w2p, fc2_b,
                                                  n2g, n2b, out);
}